// Round 7
// baseline (1249.568 us; speedup 1.0000x reference)
//
#include <hip/hip_runtime.h>
#include <hip/hip_bf16.h>
#include <math.h>

#define N_NODES 10000
#define N_EDGES 80000
#define N_ORI   12
#define N_ROWS  (N_NODES * N_ORI)

typedef __attribute__((ext_vector_type(8))) short bfrag;   // 8 bf16 = 4 VGPRs
typedef __attribute__((ext_vector_type(4))) float f32x4;

__device__ __forceinline__ float gelu_f(float x) {
    return 0.5f * x * (1.0f + erff(x * 0.70710678118654752440f));
}
__device__ __forceinline__ short f2bf(float x) {
    __hip_bfloat16 h = __float2bfloat16(x);
    return *reinterpret_cast<short*>(&h);
}

// ---------------------------------------------------------------------------
// CSR build: histogram by dst -> exclusive scan -> fill perm/srcOf.
// ---------------------------------------------------------------------------
__global__ __launch_bounds__(256) void csr_count(
    const int* __restrict__ ei, int* __restrict__ deg)
{
    int e = blockIdx.x*256 + threadIdx.x;
    if (e < N_EDGES) atomicAdd(&deg[ei[N_EDGES + e]], 1);
}

__global__ __launch_bounds__(256) void csr_scan(
    const int* __restrict__ deg, int* __restrict__ rp, int* __restrict__ wp)
{
    __shared__ int part[256];
    __shared__ int sbase[257];
    int t = threadIdx.x;
    int cs = t*40;                       // 256*40 = 10240 >= 10000
    int sum = 0;
    for (int i = 0; i < 40; i++) { int idx = cs+i; if (idx < N_NODES) sum += deg[idx]; }
    part[t] = sum;
    __syncthreads();
    if (t == 0) {
        int run = 0;
        for (int i = 0; i < 256; i++) { sbase[i] = run; run += part[i]; }
        sbase[256] = run;
    }
    __syncthreads();
    int run = sbase[t];
    for (int i = 0; i < 40; i++) {
        int idx = cs+i;
        if (idx < N_NODES) { rp[idx] = run; wp[idx] = run; run += deg[idx]; }
    }
    if (t == 0) rp[N_NODES] = sbase[256];
}

__global__ __launch_bounds__(256) void csr_fill(
    const int* __restrict__ ei, int* __restrict__ wp,
    int* __restrict__ perm, int* __restrict__ srcOf)
{
    int e = blockIdx.x*256 + threadIdx.x;
    if (e >= N_EDGES) return;
    int dn = ei[N_EDGES + e];
    int j = atomicAdd(&wp[dn], 1);
    perm[j] = e;
    srcOf[j] = ei[e];
}

// ---------------------------------------------------------------------------
// K0: weight prep (unchanged).
// ---------------------------------------------------------------------------
__global__ __launch_bounds__(256) void prep_weights(
    const float* __restrict__ W1, const float* __restrict__ W2,
    const float* __restrict__ Wb1, const float* __restrict__ Wb2,
    const float* __restrict__ Wk,
    short* __restrict__ W1B, short* __restrict__ W2B,
    short* __restrict__ W1K, short* __restrict__ W2K,
    short* __restrict__ WkB)
{
    if (blockIdx.x < 2) {
        int l = blockIdx.x;
        const float* w1 = W1 + l*16384; short* w1b = W1B + l*16384;
        const float* w2 = W2 + l*16384; short* w2b = W2B + l*16384;
        for (int i = threadIdx.x; i < 16384; i += 256) {
            int k = i >> 8, t = i & 255;
            w1b[t*64 + k] = f2bf(w1[i]);
            int t2 = i >> 6, c = i & 63;
            w2b[c*256 + t2] = f2bf(w2[i]);
        }
    } else if (blockIdx.x == 2) {
        for (int i = threadIdx.x; i < 2048; i += 256) {
            int t = i >> 5, k = i & 31;
            W1K[i] = (k < 30) ? f2bf(Wb1[k*64 + t]) : (short)0;
        }
        for (int i = threadIdx.x; i < 4096; i += 256) {
            int c = i >> 6, t = i & 63;
            W2K[i] = f2bf(Wb2[t*64 + c]);
        }
    } else {
        for (int i = threadIdx.x; i < 8192; i += 256) {
            int l = i >> 12, rem = i & 4095, k = rem >> 6, c = rem & 63;
            WkB[l*4096 + c*64 + k] = f2bf(Wk[l*4096 + k*64 + c]);
        }
    }
}

// ---------------------------------------------------------------------------
// K1: kb_ori MLP + fk (unchanged)
// ---------------------------------------------------------------------------
__global__ __launch_bounds__(64) void ori_kernel(
    const float* __restrict__ ori, const float* __restrict__ Wo1,
    const float* __restrict__ bo1, const float* __restrict__ Wo2,
    const float* __restrict__ bo2, const float* __restrict__ Wf,
    float* __restrict__ fkb)
{
    __shared__ float sh[64];
    __shared__ float skb[64];
    int i = blockIdx.x / 12, j = blockIdx.x % 12;
    int lane = threadIdx.x;
    float s = ori[3*i]*ori[3*j] + ori[3*i+1]*ori[3*j+1] + ori[3*i+2]*ori[3*j+2];
    float p1 = s, p2 = s*s, p3 = p2*s, p4 = p3*s;
    float acc = bo1[lane] + p1*Wo1[lane] + p2*Wo1[64+lane] + p3*Wo1[128+lane] + p4*Wo1[192+lane];
    sh[lane] = gelu_f(acc);
    __syncthreads();
    float acc2 = bo2[lane];
    #pragma unroll
    for (int k = 0; k < 64; k++) acc2 += sh[k] * Wo2[k*64 + lane];
    skb[lane] = gelu_f(acc2);
    __syncthreads();
    for (int l = 0; l < 2; l++) {
        float a = 0.f;
        #pragma unroll
        for (int k = 0; k < 64; k++) a += skb[k] * Wf[l*4096 + k*64 + lane];
        fkb[l*9216 + i*768 + j*64 + lane] = a;
    }
}

// ---------------------------------------------------------------------------
// K2: x = f @ We (unchanged)
// ---------------------------------------------------------------------------
__global__ __launch_bounds__(256) void embed_kernel(
    const float* __restrict__ f, const float* __restrict__ We, float* __restrict__ xe)
{
    int v = blockIdx.x*4 + (threadIdx.x >> 6);
    int lane = threadIdx.x & 63;
    if (v >= N_NODES) return;
    float acc = 0.f;
    #pragma unroll
    for (int k = 0; k < 16; k++) acc += f[v*16 + k] * We[k*64 + lane];
    xe[v*64 + lane] = acc;
}

// ---------------------------------------------------------------------------
// K3 (v3): kb MLP via MFMA, rows in DST-SORTED order (sorted edge j = row/12,
// orig edge e = perm[j]). Layer 0: fused atomic scatter (as r6). Layer 1:
// akb1 stored bf16 at SORTED row index -> gather1 streams it per dst segment.
// ---------------------------------------------------------------------------
__global__ __launch_bounds__(256, 2) void kb_mfma(
    const float* __restrict__ pos, const float* __restrict__ ori,
    const short* __restrict__ W1K, const float* __restrict__ bb1,
    const short* __restrict__ W2K, const float* __restrict__ bb2,
    const short* __restrict__ WkB, const int* __restrict__ ei,
    const int* __restrict__ perm,
    const float* __restrict__ xe, float* __restrict__ x1a,
    __hip_bfloat16* __restrict__ akb1)
{
    __shared__ short sF[256*40];
    __shared__ short sH[256*72];
    __shared__ float sEnv[256];

    int tid = threadIdx.x;
    int blockRow = blockIdx.x * 256;

    // ---- Phase A: features (row -> sorted edge j -> orig edge e) ----
    {
        int row = blockRow + tid;
        int j = row / 12, o = row - j*12;
        int e = perm[j];
        int sn = ei[e], dn = ei[N_EDGES + e];
        float rx = pos[sn*3+0] - pos[dn*3+0];
        float ry = pos[sn*3+1] - pos[dn*3+1];
        float rz = pos[sn*3+2] - pos[dn*3+2];
        float d  = sqrtf(rx*rx + ry*ry + rz*rz);
        float u2 = d*d, u4 = u2*u2, u6 = u4*u2;
        float env = (d < 1.0f) ? (1.0f - 28.0f*u6 + 48.0f*u6*d - 21.0f*u6*u2) : 0.0f;
        sEnv[tid] = env;

        float ox = ori[3*o], oy = ori[3*o+1], oz = ori[3*o+2];
        float a  = rx*ox + ry*oy + rz*oz;
        float qx = rx - a*ox, qy = ry - a*oy, qz = rz - a*oz;
        float b  = sqrtf(qx*qx + qy*qy + qz*qz);

        float fv[32];
        fv[0] = a; fv[1] = b;
        fv[2] = a*a; fv[3] = a*b; fv[4] = b*a; fv[5] = b*b;
        #pragma unroll
        for (int i = 0; i < 4; i++) { fv[6+2*i] = fv[2+i]*a; fv[7+2*i] = fv[2+i]*b; }
        #pragma unroll
        for (int i = 0; i < 8; i++) { fv[14+2*i] = fv[6+i]*a; fv[15+2*i] = fv[6+i]*b; }
        fv[30] = 0.f; fv[31] = 0.f;

        short* dst = sF + tid*40;
        #pragma unroll
        for (int blk = 0; blk < 4; blk++) {
            union { short s[8]; int4 v4; } u;
            #pragma unroll
            for (int jj = 0; jj < 8; jj++) u.s[jj] = f2bf(fv[blk*8 + jj]);
            *(int4*)(dst + blk*8) = u.v4;
        }
    }
    __syncthreads();

    int w = tid >> 6, l = tid & 63;
    int m16 = l & 15, q = l >> 4;

    // ---- FFN1: K=32 ----
    bfrag a1[4];
    #pragma unroll
    for (int mt = 0; mt < 4; mt++)
        a1[mt] = *(const bfrag*)(sF + ((w*4 + mt)*16 + m16)*40 + q*8);

    #pragma unroll
    for (int nt = 0; nt < 4; nt++) {
        bfrag bb = *(const bfrag*)(W1K + (nt*16 + m16)*32 + q*8);
        float bias = bb1[nt*16 + m16];
        #pragma unroll
        for (int mt = 0; mt < 4; mt++) {
            f32x4 acc = (f32x4){0.f,0.f,0.f,0.f};
            acc = __builtin_amdgcn_mfma_f32_16x16x32_bf16(a1[mt], bb, acc, 0, 0, 0);
            #pragma unroll
            for (int r = 0; r < 4; r++) {
                int rl = (w*4 + mt)*16 + q*4 + r;
                sH[rl*72 + nt*16 + m16] = f2bf(gelu_f(acc[r] + bias));
            }
        }
    }
    __syncthreads();

    // ---- FFN2: K=64 -> kb = gelu(.)*env back into sH (wave-local rows) ----
    bfrag a2[4][2];
    #pragma unroll
    for (int mt = 0; mt < 4; mt++)
        #pragma unroll
        for (int kc = 0; kc < 2; kc++)
            a2[mt][kc] = *(const bfrag*)(sH + ((w*4 + mt)*16 + m16)*72 + kc*32 + q*8);

    #pragma unroll
    for (int nt = 0; nt < 4; nt++) {
        f32x4 acc[4];
        #pragma unroll
        for (int mt = 0; mt < 4; mt++) acc[mt] = (f32x4){0.f,0.f,0.f,0.f};
        #pragma unroll
        for (int kc = 0; kc < 2; kc++) {
            bfrag bb = *(const bfrag*)(W2K + (nt*16 + m16)*64 + kc*32 + q*8);
            #pragma unroll
            for (int mt = 0; mt < 4; mt++)
                acc[mt] = __builtin_amdgcn_mfma_f32_16x16x32_bf16(a2[mt][kc], bb, acc[mt], 0, 0, 0);
        }
        float bias = bb2[nt*16 + m16];
        #pragma unroll
        for (int mt = 0; mt < 4; mt++) {
            #pragma unroll
            for (int r = 0; r < 4; r++) {
                int rl = (w*4 + mt)*16 + q*4 + r;
                sH[rl*72 + nt*16 + m16] = f2bf(gelu_f(acc[mt][r] + bias) * sEnv[rl]);
            }
        }
    }
    // wave-local sH rows: intra-wave DS ordering suffices, no barrier.

    // ---- akb GEMMs: kb @ Wk[l] ----
    bfrag a3[4][2];
    #pragma unroll
    for (int mt = 0; mt < 4; mt++)
        #pragma unroll
        for (int kc = 0; kc < 2; kc++)
            a3[mt][kc] = *(const bfrag*)(sH + ((w*4 + mt)*16 + m16)*72 + kc*32 + q*8);

    int oArr[4][4], snArr[4][4], dnArr[4][4];
    #pragma unroll
    for (int mt = 0; mt < 4; mt++)
        #pragma unroll
        for (int r = 0; r < 4; r++) {
            int R = blockRow + (w*4 + mt)*16 + q*4 + r;
            int j = R / 12;
            int e = perm[j];
            oArr[mt][r] = R - j*12;
            snArr[mt][r] = ei[e]; dnArr[mt][r] = ei[N_EDGES + e];
        }

    // layer 0: akb0 in regs -> fused atomic scatter
    #pragma unroll
    for (int nt = 0; nt < 4; nt++) {
        f32x4 acc[4];
        #pragma unroll
        for (int mt = 0; mt < 4; mt++) acc[mt] = (f32x4){0.f,0.f,0.f,0.f};
        #pragma unroll
        for (int kc = 0; kc < 2; kc++) {
            bfrag bb = *(const bfrag*)(WkB + (nt*16 + m16)*64 + kc*32 + q*8);
            #pragma unroll
            for (int mt = 0; mt < 4; mt++)
                acc[mt] = __builtin_amdgcn_mfma_f32_16x16x32_bf16(a3[mt][kc], bb, acc[mt], 0, 0, 0);
        }
        int col = nt*16 + m16;
        #pragma unroll
        for (int mt = 0; mt < 4; mt++)
            #pragma unroll
            for (int r = 0; r < 4; r++) {
                float val = acc[mt][r] * xe[snArr[mt][r]*64 + col];
                atomicAdd(&x1a[(size_t)dnArr[mt][r]*768 + oArr[mt][r]*64 + col], val);
            }
    }
    // layer 1: akb1 stored bf16 at sorted row index
    #pragma unroll
    for (int nt = 0; nt < 4; nt++) {
        f32x4 acc[4];
        #pragma unroll
        for (int mt = 0; mt < 4; mt++) acc[mt] = (f32x4){0.f,0.f,0.f,0.f};
        #pragma unroll
        for (int kc = 0; kc < 2; kc++) {
            bfrag bb = *(const bfrag*)(WkB + 4096 + (nt*16 + m16)*64 + kc*32 + q*8);
            #pragma unroll
            for (int mt = 0; mt < 4; mt++)
                acc[mt] = __builtin_amdgcn_mfma_f32_16x16x32_bf16(a3[mt][kc], bb, acc[mt], 0, 0, 0);
        }
        int col = nt*16 + m16;
        #pragma unroll
        for (int mt = 0; mt < 4; mt++)
            #pragma unroll
            for (int r = 0; r < 4; r++) {
                int R = blockRow + (w*4 + mt)*16 + q*4 + r;
                akb1[(size_t)R*64 + col] = __float2bfloat16(acc[mt][r]);
            }
    }
}

// ---------------------------------------------------------------------------
// K4 (NEW): layer-1 CSR gather: x1[v,o,c] = sum_{j in seg(v)} akb1[j,o,c] *
// xs1[srcOf[j],o,c].  Wave per (v,o); akb1 segment contiguous; plain store.
// ---------------------------------------------------------------------------
__global__ __launch_bounds__(256) void gather1(
    const __hip_bfloat16* __restrict__ akb, const int* __restrict__ srcOf,
    const int* __restrict__ rp, const float* __restrict__ x_in,
    float* __restrict__ x1)
{
    int w = threadIdx.x >> 6, lane = threadIdx.x & 63;
    int g = blockIdx.x*4 + w;                 // 0..119999
    int v = g / 12, o = g - v*12;
    int jb = rp[v], je = rp[v+1];
    float acc = 0.f;
    for (int j = jb; j < je; j++) {
        float a  = __bfloat162float(akb[(size_t)j*768 + o*64 + lane]);
        float xs = x_in[(size_t)srcOf[j]*768 + o*64 + lane];
        acc += a * xs;
    }
    x1[(size_t)v*768 + o*64 + lane] = acc;
}

// ---------------------------------------------------------------------------
// K5: MFMA node kernel (unchanged — known good)
// ---------------------------------------------------------------------------
__global__ __launch_bounds__(256, 2) void node_mfma(
    const float* __restrict__ x1, const float* __restrict__ fk,
    const float* __restrict__ conv_b, const float* __restrict__ ln_g,
    const float* __restrict__ ln_b,
    const short* __restrict__ W1B, const float* __restrict__ b1,
    const short* __restrict__ W2B, const float* __restrict__ pb2,
    const float* __restrict__ Wr, const float* __restrict__ br,
    const float* __restrict__ x_old, float* __restrict__ x_new,
    float* __restrict__ racc, int has_res, int write_x)
{
    __shared__ short sA1[128*72];
    __shared__ short sA2[128*136];

    int tid = threadIdx.x;
    int blockRow = blockIdx.x * 128;

    {
        int rl = tid >> 1, hf = tid & 1;
        int row = blockRow + rl;
        int rc = row < N_ROWS ? row : N_ROWS - 1;
        int v = rc / 12, pp = rc % 12;
        float h[32];
        #pragma unroll
        for (int k = 0; k < 32; k++) h[k] = 0.f;
        const float* xv = x1 + (size_t)v*768 + hf*32;
        const float* fp = fk + (size_t)pp*768 + hf*32;
        for (int o = 0; o < 12; o++) {
            const float4* xa = (const float4*)(xv + o*64);
            const float4* fa = (const float4*)(fp + o*64);
            #pragma unroll
            for (int k4 = 0; k4 < 8; k4++) {
                float4 xd = xa[k4]; float4 fd = fa[k4];
                h[4*k4+0] += xd.x*fd.x; h[4*k4+1] += xd.y*fd.y;
                h[4*k4+2] += xd.z*fd.z; h[4*k4+3] += xd.w*fd.w;
            }
        }
        const float inv12 = 1.0f/12.0f;
        float sum = 0.f;
        #pragma unroll
        for (int k = 0; k < 32; k++) { h[k] = h[k]*inv12 + conv_b[hf*32 + k]; sum += h[k]; }
        sum += __shfl_xor(sum, 1);
        float mu = sum * (1.0f/64.0f);
        float var = 0.f;
        #pragma unroll
        for (int k = 0; k < 32; k++) { float xc = h[k] - mu; var += xc*xc; }
        var += __shfl_xor(var, 1);
        float rstd = rsqrtf(var*(1.0f/64.0f) + 1e-5f);
        short* dst = sA1 + rl*72 + hf*32;
        #pragma unroll
        for (int blk = 0; blk < 4; blk++) {
            union { short s[8]; int4 v4; } u;
            #pragma unroll
            for (int jj = 0; jj < 8; jj++) {
                int k = blk*8 + jj, c = hf*32 + k;
                u.s[jj] = f2bf((h[k] - mu)*rstd*ln_g[c] + ln_b[c]);
            }
            *(int4*)(dst + blk*8) = u.v4;
        }
    }
    __syncthreads();

    int w   = tid >> 6;
    int l   = tid & 63;
    int m16 = l & 15, q = l >> 4;

    bfrag a1[2][2];
    #pragma unroll
    for (int i = 0; i < 2; i++) {
        int mt = 2*w + i;
        #pragma unroll
        for (int kc = 0; kc < 2; kc++)
            a1[i][kc] = *(const bfrag*)(sA1 + (mt*16 + m16)*72 + kc*32 + q*8);
    }

    f32x4 acc2[4][2];
    #pragma unroll
    for (int n = 0; n < 4; n++)
        #pragma unroll
        for (int i = 0; i < 2; i++)
            acc2[n][i] = (f32x4){0.f, 0.f, 0.f, 0.f};

    for (int ph = 0; ph < 2; ph++) {
        for (int ntl = 0; ntl < 8; ntl++) {
            int nt = ph*8 + ntl;
            f32x4 c0 = (f32x4){0.f,0.f,0.f,0.f};
            f32x4 c1 = (f32x4){0.f,0.f,0.f,0.f};
            #pragma unroll
            for (int kc = 0; kc < 2; kc++) {
                bfrag bb = *(const bfrag*)(W1B + (nt*16 + m16)*64 + kc*32 + q*8);
                c0 = __builtin_amdgcn_mfma_f32_16x16x32_bf16(a1[0][kc], bb, c0, 0, 0, 0);
                c1 = __builtin_amdgcn_mfma_f32_16x16x32_bf16(a1[1][kc], bb, c1, 0, 0, 0);
            }
            float bias = b1[nt*16 + m16];
            #pragma unroll
            for (int r = 0; r < 4; r++) {
                int r0 = (2*w)*16 + q*4 + r;
                int r1 = (2*w+1)*16 + q*4 + r;
                sA2[r0*136 + ntl*16 + m16] = f2bf(gelu_f(c0[r] + bias));
                sA2[r1*136 + ntl*16 + m16] = f2bf(gelu_f(c1[r] + bias));
            }
        }
        __syncthreads();
        for (int kc2 = 0; kc2 < 4; kc2++) {
            bfrag a2[2];
            #pragma unroll
            for (int i = 0; i < 2; i++)
                a2[i] = *(const bfrag*)(sA2 + ((2*w+i)*16 + m16)*136 + kc2*32 + q*8);
            #pragma unroll
            for (int nc = 0; nc < 4; nc++) {
                bfrag bb = *(const bfrag*)(W2B + (nc*16 + m16)*256 + ph*128 + kc2*32 + q*8);
                acc2[nc][0] = __builtin_amdgcn_mfma_f32_16x16x32_bf16(a2[0], bb, acc2[nc][0], 0, 0, 0);
                acc2[nc][1] = __builtin_amdgcn_mfma_f32_16x16x32_bf16(a2[1], bb, acc2[nc][1], 0, 0, 0);
            }
        }
        __syncthreads();
    }

    float p0[2][4], p1[2][4];
    #pragma unroll
    for (int i = 0; i < 2; i++) {
        #pragma unroll
        for (int r = 0; r < 4; r++) {
            int rowl = (2*w+i)*16 + q*4 + r;
            int row  = blockRow + rowl;
            bool ok  = row < N_ROWS;
            float vals[4];
            #pragma unroll
            for (int nc = 0; nc < 4; nc++) vals[nc] = acc2[nc][i][r] + pb2[nc*16 + m16];
            if (has_res && ok) {
                #pragma unroll
                for (int nc = 0; nc < 4; nc++) vals[nc] += x_old[(size_t)row*64 + nc*16 + m16];
            }
            if (write_x && ok) {
                #pragma unroll
                for (int nc = 0; nc < 4; nc++) x_new[(size_t)row*64 + nc*16 + m16] = vals[nc];
            }
            float q0 = 0.f, q1 = 0.f;
            #pragma unroll
            for (int nc = 0; nc < 4; nc++) {
                int c = nc*16 + m16;
                q0 += vals[nc]*Wr[2*c];
                q1 += vals[nc]*Wr[2*c + 1];
            }
            p0[i][r] = q0; p1[i][r] = q1;
        }
    }
    #pragma unroll
    for (int s = 1; s < 16; s <<= 1) {
        #pragma unroll
        for (int i = 0; i < 2; i++)
            #pragma unroll
            for (int r = 0; r < 4; r++) {
                p0[i][r] += __shfl_xor(p0[i][r], s);
                p1[i][r] += __shfl_xor(p1[i][r], s);
            }
    }
    if (m16 == 0) {
        #pragma unroll
        for (int i = 0; i < 2; i++)
            #pragma unroll
            for (int r = 0; r < 4; r++) {
                int row = blockRow + (2*w+i)*16 + q*4 + r;
                if (row < N_ROWS) {
                    atomicAdd(&racc[row*2 + 0], p0[i][r] + br[0]);
                    atomicAdd(&racc[row*2 + 1], p1[i][r] + br[1]);
                }
            }
    }
}

// ---------------------------------------------------------------------------
// K6: readout
// ---------------------------------------------------------------------------
__global__ __launch_bounds__(256) void final_kernel(
    const float* __restrict__ racc, const float* __restrict__ ori,
    const int* __restrict__ batch, float* __restrict__ out)
{
    int v = blockIdx.x*256 + threadIdx.x;
    if (v >= N_NODES) return;
    float srs = 0.f, vx = 0.f, vy = 0.f, vz = 0.f;
    #pragma unroll
    for (int p = 0; p < 12; p++) {
        float r0 = racc[v*24 + 2*p], r1 = racc[v*24 + 2*p + 1];
        srs += r0;
        vx += r1*ori[3*p]; vy += r1*ori[3*p+1]; vz += r1*ori[3*p+2];
    }
    const float sc = 1.0f/24.0f;
    int g = batch[v];
    atomicAdd(&out[g], srs*sc);
    atomicAdd(&out[16 + g*3 + 0], vx*sc);
    atomicAdd(&out[16 + g*3 + 1], vy*sc);
    atomicAdd(&out[16 + g*3 + 2], vz*sc);
}

extern "C" void kernel_launch(void* const* d_in, const int* in_sizes, int n_in,
                              void* d_out, int out_size, void* d_ws, size_t ws_size,
                              hipStream_t stream) {
    const float* pos    = (const float*)d_in[0];
    const float* f      = (const float*)d_in[1];
    const float* ori    = (const float*)d_in[2];
    const int*   ei     = (const int*)  d_in[3];
    const int*   batch  = (const int*)  d_in[4];
    const float* Wb1    = (const float*)d_in[5];
    const float* bb1    = (const float*)d_in[6];
    const float* Wb2    = (const float*)d_in[7];
    const float* bb2    = (const float*)d_in[8];
    const float* Wo1    = (const float*)d_in[9];
    const float* bo1    = (const float*)d_in[10];
    const float* Wo2    = (const float*)d_in[11];
    const float* bo2    = (const float*)d_in[12];
    const float* We     = (const float*)d_in[13];
    const float* Wk     = (const float*)d_in[14];
    const float* Wf     = (const float*)d_in[15];
    const float* conv_b = (const float*)d_in[16];
    const float* ln_g   = (const float*)d_in[17];
    const float* ln_b   = (const float*)d_in[18];
    const float* W1     = (const float*)d_in[19];
    const float* b1     = (const float*)d_in[20];
    const float* W2     = (const float*)d_in[21];
    const float* b2     = (const float*)d_in[22];
    const float* Wr     = (const float*)d_in[23];
    const float* br     = (const float*)d_in[24];
    float* out = (float*)d_out;

    float* ws   = (float*)d_ws;
    float* xe   = ws;                       //   640,000 f32
    float* xs1  = xe   + 640000;            // 7,680,000
    float* x1a  = xs1  + 7680000;           // 7,680,000
    float* racc = x1a  + 7680000;           //   240,000
    float* fkb  = racc + 240000;            //    18,432
    short* w1b  = (short*)(fkb + 18432);    //    32,768 shorts (2 layers)
    short* w2b  = w1b + 32768;              //    32,768 shorts
    short* w1k  = w2b + 32768;              //     2,048 shorts
    short* w2k  = w1k + 2048;               //     4,096 shorts
    short* wkb  = w2k + 4096;               //     8,192 shorts
    int*   deg  = (int*)(wkb + 8192);       //    10,000 ints
    int*   rp   = deg + 10000;              //    10,001 ints
    int*   wp   = rp  + 10001;              //    10,000 ints
    int*   perm = wp  + 10000;              //    80,000 ints
    int*   srcOf= perm+ 80000;              //    80,000 ints
    int*   pad_ = srcOf + 80000;            //  align up
    __hip_bfloat16* akb1 = (__hip_bfloat16*)(pad_ + 3);     // 61,440,000 bf16

    hipMemsetAsync(out,  0, 64*sizeof(float), stream);
    hipMemsetAsync(racc, 0, 240000*sizeof(float), stream);
    hipMemsetAsync(x1a,  0, 7680000*sizeof(float), stream);
    hipMemsetAsync(deg,  0, 10000*sizeof(int), stream);

    // CSR by dst
    csr_count<<<313, 256, 0, stream>>>(ei, deg);
    csr_scan <<<1,   256, 0, stream>>>(deg, rp, wp);
    csr_fill <<<313, 256, 0, stream>>>(ei, wp, perm, srcOf);

    prep_weights<<<4,    256, 0, stream>>>(W1, W2, Wb1, Wb2, Wk,
                                           w1b, w2b, w1k, w2k, wkb);
    ori_kernel  <<<144,  64, 0, stream>>>(ori, Wo1, bo1, Wo2, bo2, Wf, fkb);
    embed_kernel<<<2500, 256, 0, stream>>>(f, We, xe);

    // kb MLP + akb GEMMs + fused layer-0 scatter + sorted akb1 store
    kb_mfma     <<<3750, 256, 0, stream>>>(pos, ori, w1k, bb1, w2k, bb2,
                                           wkb, ei, perm, xe, x1a, akb1);

    // layer 0 node
    node_mfma   <<<938,  256, 0, stream>>>(x1a, fkb, conv_b, ln_g, ln_b,
                                           w1b, b1, w2b, b2, Wr, br,
                                           xs1, xs1, racc, /*res=*/0, /*write=*/1);
    // layer 1: CSR gather (writes x1a fully -> no memset, no atomics)
    gather1     <<<30000,256, 0, stream>>>(akb1, srcOf, rp, xs1, x1a);
    node_mfma   <<<938,  256, 0, stream>>>(x1a, fkb + 9216, conv_b + 64, ln_g + 64, ln_b + 64,
                                           w1b + 16384, b1 + 256, w2b + 16384, b2 + 64,
                                           Wr + 128, br + 2,
                                           xs1, xs1, racc, /*res=*/1, /*write=*/0);

    final_kernel<<<40,   256, 0, stream>>>(racc, ori, batch, out);
}